// Round 3
// baseline (473.044 us; speedup 1.0000x reference)
//
#include <hip/hip_runtime.h>

// ---------------------------------------------------------------------------
// NonLocalBlockND: B=8, C=1024, Ci=512, N=T*H*W=2048
//   proj:   theta/phi/g = W(Ci,C) @ x(C,N) + b     per batch
//   attn:   f = theta^T phi (N,N); softmax; y = f @ g^T  -> (N,Ci)
//   out:    BN(W_w @ y^T + W_b) + x
// Strategy: fp16 MFMA (16x16x32) GEMMs, fp32 scores+softmax, m97-style
// 128x128xBK64 tiles with global_load_lds(16B) staging, 256 thr / 4 waves.
// ---------------------------------------------------------------------------

#define B_  8
#define C_  1024
#define CI_ 512
#define N_  2048

typedef _Float16 half_t;
typedef __attribute__((ext_vector_type(8))) _Float16 f16x8;
typedef __attribute__((ext_vector_type(4))) float     f32x4;

__device__ __forceinline__ void gload16(const void* g, void* l) {
  __builtin_amdgcn_global_load_lds(
      (__attribute__((address_space(1))) unsigned int*)(g),
      (__attribute__((address_space(3))) unsigned int*)(l),
      16, 0, 0);
}

// ---------------------------------------------------------------------------
// 128x128 tile GEMM mainloop, BK=64, 256 threads (4 waves, 2x2 wave grid,
// each wave 64x64 = 4x4 fragments of 16x16). A: (M,K) K-contig; B: (N,K)
// K-contig (i.e. C = A * B^T in row-major terms). Single-buffered LDS,
// 2 barriers per K-step (m97 structure).
// ---------------------------------------------------------------------------
__device__ __forceinline__ void gemm128(const half_t* Ag, long lda,
                                        const half_t* Bg, long ldb,
                                        int K,
                                        half_t* lA, half_t* lB,
                                        f32x4 acc[4][4])
{
  const int tid  = threadIdx.x;
  const int lane = tid & 63;
  const int wid  = tid >> 6;
  const int wm   = wid >> 1, wn = wid & 1;
  const int frow = lane & 15;            // row within 16x16 fragment
  const int fk   = (lane >> 4) << 3;     // k-offset (elements) of this lane group

  for (int k0 = 0; k0 < K; k0 += 64) {
    // stage A tile: 128 rows x 64 halves = 16KB = 1024 x 16B chunks
#pragma unroll
    for (int it = 0; it < 4; ++it) {
      int c = it * 256 + tid;            // chunk id
      int row = c >> 3, slot = c & 7;    // 8 chunks per row
      gload16(Ag + (long)row * lda + (k0 + slot * 8), (char*)lA + c * 16);
    }
#pragma unroll
    for (int it = 0; it < 4; ++it) {
      int c = it * 256 + tid;
      int row = c >> 3, slot = c & 7;
      gload16(Bg + (long)row * ldb + (k0 + slot * 8), (char*)lB + c * 16);
    }
    __syncthreads();   // drains vmcnt -> LDS tiles complete
#pragma unroll
    for (int kk = 0; kk < 2; ++kk) {
      f16x8 af[4], bfr[4];
#pragma unroll
      for (int i = 0; i < 4; ++i)
        af[i] = *(const f16x8*)(lA + (wm * 64 + i * 16 + frow) * 64 + kk * 32 + fk);
#pragma unroll
      for (int j = 0; j < 4; ++j)
        bfr[j] = *(const f16x8*)(lB + (wn * 64 + j * 16 + frow) * 64 + kk * 32 + fk);
#pragma unroll
      for (int i = 0; i < 4; ++i)
#pragma unroll
        for (int j = 0; j < 4; ++j)
          acc[i][j] = __builtin_amdgcn_mfma_f32_16x16x32_f16(af[i], bfr[j], acc[i][j], 0, 0, 0);
    }
    __syncthreads();
  }
}

__device__ __forceinline__ void zero_acc(f32x4 acc[4][4]) {
  f32x4 z = {0.f, 0.f, 0.f, 0.f};
#pragma unroll
  for (int i = 0; i < 4; ++i)
#pragma unroll
    for (int j = 0; j < 4; ++j) acc[i][j] = z;
}

// ---------------------------------------------------------------------------
// prep: cast weights to fp16 (Wcat = [theta;phi;g] (1536,1024), Wfin (1024,512))
// and fold BN+bias into per-channel scale/shift.
// ---------------------------------------------------------------------------
__global__ __launch_bounds__(256) void k_prep(
    const float* theta_w, const float* phi_w, const float* g_w,
    const float* W_w, const float* W_b,
    const float* gamma, const float* beta, const float* mean, const float* var,
    half_t* Wcat, half_t* Wfin, float* bnA, float* bnB)
{
  const int PW = CI_ * C_;   // 524288
  int idx = blockIdx.x * 256 + threadIdx.x;
  if (idx < PW)               Wcat[idx] = (half_t)theta_w[idx];
  else if (idx < 2 * PW)      Wcat[idx] = (half_t)phi_w[idx - PW];
  else if (idx < 3 * PW)      Wcat[idx] = (half_t)g_w[idx - 2 * PW];
  else if (idx < 4 * PW)      Wfin[idx - 3 * PW] = (half_t)W_w[idx - 3 * PW];
  else if (idx < 4 * PW + C_) {
    int o = idx - 4 * PW;
    float sc = gamma[o] * rsqrtf(var[o] + 1e-5f);
    bnA[o] = sc;
    bnB[o] = (W_b[o] - mean[o]) * sc + beta[o];
  }
}

// ---------------------------------------------------------------------------
// transpose+cast: x (B,C,N) f32 -> xT (B,N,C) f16
// ---------------------------------------------------------------------------
__global__ __launch_bounds__(256) void k_transpose(const float* x, half_t* xT)
{
  __shared__ float t[32][33];
  int b = blockIdx.z, c0 = blockIdx.y * 32, n0 = blockIdx.x * 32;
  int tx = threadIdx.x, ty = threadIdx.y;
  const float* xp = x + ((long)b * C_ + c0) * N_ + n0;
#pragma unroll
  for (int j = 0; j < 4; ++j)
    t[ty + j * 8][tx] = xp[(long)(ty + j * 8) * N_ + tx];
  __syncthreads();
  half_t* xo = xT + ((long)b * N_ + n0) * C_ + c0;
#pragma unroll
  for (int j = 0; j < 4; ++j)
    xo[(long)(ty + j * 8) * C_ + tx] = (half_t)t[tx][ty + j * 8];
}

// ---------------------------------------------------------------------------
// projections: Wcat(1536,1024) @ xT[b](2048,1024)^T.
// rows 0..511 -> thetaT (B,N,Ci) [transposed write, +theta_b]
// rows 512..1023 -> phiT (B,N,Ci) [+phi_b]
// rows 1024..1535 -> gmat (B,Ci,N) [natural write, +g_b]
// ---------------------------------------------------------------------------
typedef __attribute__((ext_vector_type(4))) _Float16 f16x4;

__global__ __launch_bounds__(256) void k_proj(
    const half_t* Wcat, const half_t* xT,
    const float* theta_b, const float* phi_b, const float* g_b,
    half_t* thetaT, half_t* phiT, half_t* gmat)
{
  __shared__ __align__(16) half_t lA[128 * 64];
  __shared__ __align__(16) half_t lB[128 * 64];
  int b = blockIdx.z, m0 = blockIdx.y * 128, n0 = blockIdx.x * 128;
  f32x4 acc[4][4];
  zero_acc(acc);
  gemm128(Wcat + (long)m0 * C_, C_, xT + ((long)b * N_ + n0) * C_, C_, C_, lA, lB, acc);

  int lane = threadIdx.x & 63, wid = threadIdx.x >> 6;
  int wm = wid >> 1, wn = wid & 1;
  int r4 = (lane >> 4) * 4, cc = lane & 15;
#pragma unroll
  for (int i = 0; i < 4; ++i) {
    int orow = m0 + wm * 64 + i * 16 + r4;
#pragma unroll
    for (int j = 0; j < 4; ++j) {
      int ncol = n0 + wn * 64 + j * 16 + cc;
      f32x4 v = acc[i][j];
      if (m0 < 512) {
        int o = orow;
        f16x4 w = { (half_t)(v[0] + theta_b[o]), (half_t)(v[1] + theta_b[o + 1]),
                    (half_t)(v[2] + theta_b[o + 2]), (half_t)(v[3] + theta_b[o + 3]) };
        *(f16x4*)(thetaT + ((long)b * N_ + ncol) * CI_ + o) = w;
      } else if (m0 < 1024) {
        int o = orow - 512;
        f16x4 w = { (half_t)(v[0] + phi_b[o]), (half_t)(v[1] + phi_b[o + 1]),
                    (half_t)(v[2] + phi_b[o + 2]), (half_t)(v[3] + phi_b[o + 3]) };
        *(f16x4*)(phiT + ((long)b * N_ + ncol) * CI_ + o) = w;
      } else {
        int o = orow - 1024;
#pragma unroll
        for (int r = 0; r < 4; ++r)
          gmat[((long)b * CI_ + o + r) * N_ + ncol] = (half_t)(v[r] + g_b[o + r]);
      }
    }
  }
}

// ---------------------------------------------------------------------------
// scores: f[b, nloc, m] (f32) = thetaT[b, c0+nloc, :] . phiT[b, m, :]
// ---------------------------------------------------------------------------
__global__ __launch_bounds__(256) void k_qk(
    const half_t* thetaT, const half_t* phiT, float* fbuf, int c0, int rows)
{
  __shared__ __align__(16) half_t lA[128 * 64];
  __shared__ __align__(16) half_t lB[128 * 64];
  int b = blockIdx.z, m0 = blockIdx.y * 128, n0 = blockIdx.x * 128;
  f32x4 acc[4][4];
  zero_acc(acc);
  gemm128(thetaT + ((long)b * N_ + c0 + m0) * CI_, CI_,
          phiT   + ((long)b * N_ + n0) * CI_,      CI_, CI_, lA, lB, acc);

  int lane = threadIdx.x & 63, wid = threadIdx.x >> 6;
  int wm = wid >> 1, wn = wid & 1;
  int r4 = (lane >> 4) * 4, cc = lane & 15;
#pragma unroll
  for (int i = 0; i < 4; ++i) {
    int mr = m0 + wm * 64 + i * 16 + r4;
#pragma unroll
    for (int j = 0; j < 4; ++j) {
      int nc = n0 + wn * 64 + j * 16 + cc;
      float* dst = fbuf + ((long)b * rows + mr) * N_ + nc;
#pragma unroll
      for (int r = 0; r < 4; ++r) dst[(long)r * N_] = acc[i][j][r];
    }
  }
}

// ---------------------------------------------------------------------------
// softmax over rows of fbuf (f32, len 2048); writes fp16 probabilities
// in-place over the start of each row (row stride stays 2048 f32 = 4096 f16).
// ---------------------------------------------------------------------------
__global__ __launch_bounds__(256) void k_softmax(float* fbuf)
{
  long row = blockIdx.x;
  float* rp = fbuf + row * N_;
  int t = threadIdx.x, lane = t & 63, wid = t >> 6;
  f32x4 a = *(const f32x4*)(rp + t * 8);
  f32x4 c = *(const f32x4*)(rp + t * 8 + 4);
  float m = fmaxf(fmaxf(fmaxf(a[0], a[1]), fmaxf(a[2], a[3])),
                  fmaxf(fmaxf(c[0], c[1]), fmaxf(c[2], c[3])));
#pragma unroll
  for (int o = 1; o < 64; o <<= 1) m = fmaxf(m, __shfl_xor(m, o));
  __shared__ float red[8];
  if (lane == 0) red[wid] = m;
  __syncthreads();
  m = fmaxf(fmaxf(red[0], red[1]), fmaxf(red[2], red[3]));
  float e[8];
  e[0] = __expf(a[0] - m); e[1] = __expf(a[1] - m);
  e[2] = __expf(a[2] - m); e[3] = __expf(a[3] - m);
  e[4] = __expf(c[0] - m); e[5] = __expf(c[1] - m);
  e[6] = __expf(c[2] - m); e[7] = __expf(c[3] - m);
  float s = ((e[0] + e[1]) + (e[2] + e[3])) + ((e[4] + e[5]) + (e[6] + e[7]));
#pragma unroll
  for (int o = 1; o < 64; o <<= 1) s += __shfl_xor(s, o);
  if (lane == 0) red[4 + wid] = s;
  __syncthreads();
  s = (red[4] + red[5]) + (red[6] + red[7]);
  float inv = 1.0f / s;
  f16x8 ph;
#pragma unroll
  for (int k = 0; k < 8; ++k) ph[k] = (half_t)(e[k] * inv);
  *(f16x8*)((half_t*)rp + t * 8) = ph;   // all reads of this row happened pre-barrier
}

// ---------------------------------------------------------------------------
// PV: y[b, c0+nloc, ci] (f16) = sum_m P[b,nloc,m] * gmat[b,ci,m]
// P rows live at stride 4096 f16 inside fbuf.
// ---------------------------------------------------------------------------
__global__ __launch_bounds__(256) void k_pv(
    const half_t* P, const half_t* gmat, half_t* ybuf, int c0, int rows)
{
  __shared__ __align__(16) half_t lA[128 * 64];
  __shared__ __align__(16) half_t lB[128 * 64];
  int b = blockIdx.z, m0 = blockIdx.y * 128, n0 = blockIdx.x * 128;
  f32x4 acc[4][4];
  zero_acc(acc);
  gemm128(P + ((long)b * rows + m0) * (N_ * 2), N_ * 2,
          gmat + ((long)b * CI_ + n0) * N_,     N_, N_, lA, lB, acc);

  int lane = threadIdx.x & 63, wid = threadIdx.x >> 6;
  int wm = wid >> 1, wn = wid & 1;
  int r4 = (lane >> 4) * 4, cc = lane & 15;
#pragma unroll
  for (int i = 0; i < 4; ++i) {
    int mr = m0 + wm * 64 + i * 16 + r4;
#pragma unroll
    for (int j = 0; j < 4; ++j) {
      int nc = n0 + wn * 64 + j * 16 + cc;
#pragma unroll
      for (int r = 0; r < 4; ++r)
        ybuf[((long)b * N_ + c0 + mr + r) * CI_ + nc] = (half_t)acc[i][j][r];
    }
  }
}

// ---------------------------------------------------------------------------
// final: out[b,o,n] = acc(Wfin[o,:].y[b,n,:]) * bnA[o] + bnB[o] + x[b,o,n]
// ---------------------------------------------------------------------------
__global__ __launch_bounds__(256) void k_final(
    const half_t* Wfin, const half_t* ybuf,
    const float* bnA, const float* bnB, const float* x, float* out)
{
  __shared__ __align__(16) half_t lA[128 * 64];
  __shared__ __align__(16) half_t lB[128 * 64];
  int b = blockIdx.z, m0 = blockIdx.y * 128, n0 = blockIdx.x * 128;
  f32x4 acc[4][4];
  zero_acc(acc);
  gemm128(Wfin + (long)m0 * CI_, CI_,
          ybuf + ((long)b * N_ + n0) * CI_, CI_, CI_, lA, lB, acc);

  int lane = threadIdx.x & 63, wid = threadIdx.x >> 6;
  int wm = wid >> 1, wn = wid & 1;
  int r4 = (lane >> 4) * 4, cc = lane & 15;
#pragma unroll
  for (int i = 0; i < 4; ++i) {
    int o = m0 + wm * 64 + i * 16 + r4;
#pragma unroll
    for (int j = 0; j < 4; ++j) {
      int nc = n0 + wn * 64 + j * 16 + cc;
#pragma unroll
      for (int r = 0; r < 4; ++r) {
        long idx = ((long)b * C_ + o + r) * N_ + nc;
        out[idx] = acc[i][j][r] * bnA[o + r] + bnB[o + r] + x[idx];
      }
    }
  }
}

// ---------------------------------------------------------------------------
extern "C" void kernel_launch(void* const* d_in, const int* in_sizes, int n_in,
                              void* d_out, int out_size, void* d_ws, size_t ws_size,
                              hipStream_t stream)
{
  const float* x       = (const float*)d_in[0];
  const float* g_w     = (const float*)d_in[1];
  const float* g_b     = (const float*)d_in[2];
  const float* theta_w = (const float*)d_in[3];
  const float* theta_b = (const float*)d_in[4];
  const float* phi_w   = (const float*)d_in[5];
  const float* phi_b   = (const float*)d_in[6];
  const float* W_w     = (const float*)d_in[7];
  const float* W_b     = (const float*)d_in[8];
  const float* gamma   = (const float*)d_in[9];
  const float* beta    = (const float*)d_in[10];
  const float* mean    = (const float*)d_in[11];
  const float* var     = (const float*)d_in[12];
  float* out = (float*)d_out;

  char* p = (char*)d_ws;
  auto alloc = [&](size_t bytes) {
    char* r = p; p += (bytes + 255) & ~(size_t)255; return r;
  };
  half_t* xT     = (half_t*)alloc((size_t)B_ * N_ * C_ * 2);    // 32 MB
  half_t* Wcat   = (half_t*)alloc((size_t)1536 * C_ * 2);       // 3 MB
  half_t* Wfin   = (half_t*)alloc((size_t)C_ * CI_ * 2);        // 1 MB
  half_t* thetaT = (half_t*)alloc((size_t)B_ * N_ * CI_ * 2);   // 16 MB
  half_t* phiT   = (half_t*)alloc((size_t)B_ * N_ * CI_ * 2);   // 16 MB
  half_t* gmat   = (half_t*)alloc((size_t)B_ * CI_ * N_ * 2);   // 16 MB
  half_t* ybuf   = (half_t*)alloc((size_t)B_ * N_ * CI_ * 2);   // 16 MB
  float*  bnA    = (float*)alloc(C_ * 4);
  float*  bnB    = (float*)alloc(C_ * 4);
  size_t fixed = (size_t)(p - (char*)d_ws);

  // choose score-chunk rows to fit ws
  int rows;
  if      (fixed + (size_t)B_ * 2048 * N_ * 4 <= ws_size) rows = 2048;
  else if (fixed + (size_t)B_ * 1024 * N_ * 4 <= ws_size) rows = 1024;
  else if (fixed + (size_t)B_ *  512 * N_ * 4 <= ws_size) rows = 512;
  else if (fixed + (size_t)B_ *  256 * N_ * 4 <= ws_size) rows = 256;
  else rows = 128;
  float* fbuf = (float*)alloc((size_t)B_ * rows * N_ * 4);

  k_prep<<<dim3((4 * CI_ * C_ + C_) / 256 + 1), 256, 0, stream>>>(
      theta_w, phi_w, g_w, W_w, W_b, gamma, beta, mean, var, Wcat, Wfin, bnA, bnB);
  k_transpose<<<dim3(N_ / 32, C_ / 32, B_), dim3(32, 8), 0, stream>>>(x, xT);
  k_proj<<<dim3(N_ / 128, 1536 / 128, B_), 256, 0, stream>>>(
      Wcat, xT, theta_b, phi_b, g_b, thetaT, phiT, gmat);
  for (int c0 = 0; c0 < N_; c0 += rows) {
    k_qk<<<dim3(N_ / 128, rows / 128, B_), 256, 0, stream>>>(thetaT, phiT, fbuf, c0, rows);
    k_softmax<<<dim3(B_ * rows), 256, 0, stream>>>(fbuf);
    k_pv<<<dim3(CI_ / 128, rows / 128, B_), 256, 0, stream>>>(
        (const half_t*)fbuf, gmat, ybuf, c0, rows);
  }
  k_final<<<dim3(N_ / 128, C_ / 128, B_), 256, 0, stream>>>(Wfin, ybuf, bnA, bnB, x, out);
}

// Round 5
// 434.870 us; speedup vs baseline: 1.0878x; 1.0878x over previous
//
#include <hip/hip_runtime.h>

// ---------------------------------------------------------------------------
// NonLocalBlockND: B=8, C=1024, Ci=512, N=T*H*W=2048
// fp16 MFMA GEMMs (m97-style 128x128xBK64 mainloop, global_load_lds 16B),
// fp32 scores+softmax. R4: LDS-staged COALESCED epilogues on all GEMMs
// (prev: scalar/8B scattered stores -> latency-bound, k_final 110us @ 6% mfma).
// ---------------------------------------------------------------------------

#define B_  8
#define C_  1024
#define CI_ 512
#define N_  2048

typedef _Float16 half_t;
typedef __attribute__((ext_vector_type(8))) _Float16 f16x8;
typedef __attribute__((ext_vector_type(4))) _Float16 f16x4;
typedef __attribute__((ext_vector_type(4))) float     f32x4;

__device__ __forceinline__ void gload16(const void* g, void* l) {
  __builtin_amdgcn_global_load_lds(
      (__attribute__((address_space(1))) unsigned int*)(g),
      (__attribute__((address_space(3))) unsigned int*)(l),
      16, 0, 0);
}

// ---------------------------------------------------------------------------
// 128x128 tile GEMM mainloop, BK=64, 256 threads (4 waves, 2x2), unchanged
// from R3 (known-correct). A:(M,K) K-contig; B:(N,K) K-contig; C = A*B^T.
// ---------------------------------------------------------------------------
__device__ __forceinline__ void gemm128(const half_t* Ag, long lda,
                                        const half_t* Bg, long ldb,
                                        int K,
                                        half_t* lA, half_t* lB,
                                        f32x4 acc[4][4])
{
  const int tid  = threadIdx.x;
  const int lane = tid & 63;
  const int wid  = tid >> 6;
  const int wm   = wid >> 1, wn = wid & 1;
  const int frow = lane & 15;
  const int fk   = (lane >> 4) << 3;

  for (int k0 = 0; k0 < K; k0 += 64) {
#pragma unroll
    for (int it = 0; it < 4; ++it) {
      int c = it * 256 + tid;
      int row = c >> 3, slot = c & 7;
      gload16(Ag + (long)row * lda + (k0 + slot * 8), (char*)lA + c * 16);
    }
#pragma unroll
    for (int it = 0; it < 4; ++it) {
      int c = it * 256 + tid;
      int row = c >> 3, slot = c & 7;
      gload16(Bg + (long)row * ldb + (k0 + slot * 8), (char*)lB + c * 16);
    }
    __syncthreads();
#pragma unroll
    for (int kk = 0; kk < 2; ++kk) {
      f16x8 af[4], bfr[4];
#pragma unroll
      for (int i = 0; i < 4; ++i)
        af[i] = *(const f16x8*)(lA + (wm * 64 + i * 16 + frow) * 64 + kk * 32 + fk);
#pragma unroll
      for (int j = 0; j < 4; ++j)
        bfr[j] = *(const f16x8*)(lB + (wn * 64 + j * 16 + frow) * 64 + kk * 32 + fk);
#pragma unroll
      for (int i = 0; i < 4; ++i)
#pragma unroll
        for (int j = 0; j < 4; ++j)
          acc[i][j] = __builtin_amdgcn_mfma_f32_16x16x32_f16(af[i], bfr[j], acc[i][j], 0, 0, 0);
    }
    __syncthreads();
  }
}

__device__ __forceinline__ void zero_acc(f32x4 acc[4][4]) {
  f32x4 z = {0.f, 0.f, 0.f, 0.f};
#pragma unroll
  for (int i = 0; i < 4; ++i)
#pragma unroll
    for (int j = 0; j < 4; ++j) acc[i][j] = z;
}

// Dump one wave's 64x64 acc tile into ep[64][128] (f32) if wm==pass.
// bias_row: per-LDS-row bias (nullptr = none), already offset for this pass.
__device__ __forceinline__ void dump_acc(float* ep, const f32x4 acc[4][4],
                                         int wm, int wn, int lane, int pass,
                                         const float* bias_row)
{
  if (wm != pass) return;
  int r4 = (lane >> 4) * 4, cc = lane & 15;
#pragma unroll
  for (int i = 0; i < 4; ++i) {
#pragma unroll
    for (int r = 0; r < 4; ++r) {
      int row = i * 16 + r4 + r;
      float bv = bias_row ? bias_row[row] : 0.0f;
#pragma unroll
      for (int j = 0; j < 4; ++j)
        ep[row * 128 + wn * 64 + j * 16 + cc] = acc[i][j][r] + bv;
    }
  }
}

// ---------------------------------------------------------------------------
// prep: cast weights to fp16; fold BN+bias into per-channel scale/shift.
// ---------------------------------------------------------------------------
__global__ __launch_bounds__(256) void k_prep(
    const float* theta_w, const float* phi_w, const float* g_w,
    const float* W_w, const float* W_b,
    const float* gamma, const float* beta, const float* mean, const float* var,
    half_t* Wcat, half_t* Wfin, float* bnA, float* bnB)
{
  const int PW = CI_ * C_;
  int idx = blockIdx.x * 256 + threadIdx.x;
  if (idx < PW)               Wcat[idx] = (half_t)theta_w[idx];
  else if (idx < 2 * PW)      Wcat[idx] = (half_t)phi_w[idx - PW];
  else if (idx < 3 * PW)      Wcat[idx] = (half_t)g_w[idx - 2 * PW];
  else if (idx < 4 * PW)      Wfin[idx - 3 * PW] = (half_t)W_w[idx - 3 * PW];
  else if (idx < 4 * PW + C_) {
    int o = idx - 4 * PW;
    float sc = gamma[o] * rsqrtf(var[o] + 1e-5f);
    bnA[o] = sc;
    bnB[o] = (W_b[o] - mean[o]) * sc + beta[o];
  }
}

// ---------------------------------------------------------------------------
// transpose+cast: x (B,C,N) f32 -> xT (B,N,C) f16
// ---------------------------------------------------------------------------
__global__ __launch_bounds__(256) void k_transpose(const float* x, half_t* xT)
{
  __shared__ float t[32][33];
  int b = blockIdx.z, c0 = blockIdx.y * 32, n0 = blockIdx.x * 32;
  int tx = threadIdx.x, ty = threadIdx.y;
  const float* xp = x + ((long)b * C_ + c0) * N_ + n0;
#pragma unroll
  for (int j = 0; j < 4; ++j)
    t[ty + j * 8][tx] = xp[(long)(ty + j * 8) * N_ + tx];
  __syncthreads();
  half_t* xo = xT + ((long)b * N_ + n0) * C_ + c0;
#pragma unroll
  for (int j = 0; j < 4; ++j)
    xo[(long)(ty + j * 8) * C_ + tx] = (half_t)t[tx][ty + j * 8];
}

// ---------------------------------------------------------------------------
// projections: Wcat(1536,1024) @ xT[b](2048,1024)^T, LDS-staged epilogues.
// rows 0..511 -> thetaT (B,N,Ci)  [transposed readout, +theta_b]
// rows 512..1023 -> phiT (B,N,Ci) [transposed readout, +phi_b]
// rows 1024..1535 -> gmat (B,Ci,N)[row-major readout,  +g_b]
// ---------------------------------------------------------------------------
__global__ __launch_bounds__(256) void k_proj(
    const half_t* Wcat, const half_t* xT,
    const float* theta_b, const float* phi_b, const float* g_b,
    half_t* thetaT, half_t* phiT, half_t* gmat)
{
  __shared__ __align__(16) char smem[32768];
  half_t* lA = (half_t*)smem;
  half_t* lB = (half_t*)(smem + 16384);
  float*  ep = (float*)smem;

  int b = blockIdx.z, m0 = blockIdx.y * 128, n0 = blockIdx.x * 128;
  f32x4 acc[4][4];
  zero_acc(acc);
  gemm128(Wcat + (long)m0 * C_, C_, xT + ((long)b * N_ + n0) * C_, C_, C_, lA, lB, acc);

  int lane = threadIdx.x & 63, wid = threadIdx.x >> 6;
  int wm = wid >> 1, wn = wid & 1;
  int t = threadIdx.x;

  const float* bias = (m0 < 512) ? theta_b : (m0 < 1024) ? phi_b : g_b;
  int m0sub = (m0 < 512) ? m0 : (m0 < 1024) ? m0 - 512 : m0 - 1024;

#pragma unroll
  for (int pass = 0; pass < 2; ++pass) {
    __syncthreads();
    dump_acc(ep, acc, wm, wn, lane, pass, bias + m0sub + pass * 64);
    __syncthreads();
    if (m0 < 1024) {
      // transposed readout: out[n0+ncol][o] f16, contiguous along o.
      half_t* basep = (m0 < 512) ? thetaT : phiT;
      int ncol = t >> 1, ob = (t & 1) * 32;
      half_t* dst = basep + ((long)b * N_ + n0 + ncol) * CI_
                          + (m0sub + pass * 64 + ob);
#pragma unroll
      for (int k2 = 0; k2 < 4; ++k2) {
        f16x8 w;
#pragma unroll
        for (int e = 0; e < 8; ++e)
          w[e] = (half_t)ep[(ob + k2 * 8 + e) * 128 + ncol];
        *(f16x8*)(dst + k2 * 8) = w;
      }
    } else {
      // row-major readout: gmat[(b*CI+o)*N + n0+col] f16.
#pragma unroll
      for (int k = 0; k < 8; ++k) {
        int lin = t * 4 + k * 1024;
        int row = lin >> 7, col = lin & 127;
        int o = m0sub + pass * 64 + row;
        f32x4 v = *(const f32x4*)(ep + lin);
        f16x4 w = { (half_t)v[0], (half_t)v[1], (half_t)v[2], (half_t)v[3] };
        *(f16x4*)(gmat + ((long)b * CI_ + o) * N_ + n0 + col) = w;
      }
    }
  }
}

// ---------------------------------------------------------------------------
// scores: f[b, nloc, m] (f32) = thetaT[b, c0+nloc, :] . phiT[b, m, :]
// ---------------------------------------------------------------------------
__global__ __launch_bounds__(256) void k_qk(
    const half_t* thetaT, const half_t* phiT, float* fbuf, int c0, int rows)
{
  __shared__ __align__(16) char smem[32768];
  half_t* lA = (half_t*)smem;
  half_t* lB = (half_t*)(smem + 16384);
  float*  ep = (float*)smem;

  int b = blockIdx.z, m0 = blockIdx.y * 128, n0 = blockIdx.x * 128;
  f32x4 acc[4][4];
  zero_acc(acc);
  gemm128(thetaT + ((long)b * N_ + c0 + m0) * CI_, CI_,
          phiT   + ((long)b * N_ + n0) * CI_,      CI_, CI_, lA, lB, acc);

  int lane = threadIdx.x & 63, wid = threadIdx.x >> 6;
  int wm = wid >> 1, wn = wid & 1;
  int t = threadIdx.x;
#pragma unroll
  for (int pass = 0; pass < 2; ++pass) {
    __syncthreads();
    dump_acc(ep, acc, wm, wn, lane, pass, nullptr);
    __syncthreads();
#pragma unroll
    for (int k = 0; k < 8; ++k) {
      int lin = t * 4 + k * 1024;
      int row = lin >> 7, col = lin & 127;
      int mr = m0 + pass * 64 + row;
      *(f32x4*)(fbuf + ((long)b * rows + mr) * N_ + n0 + col) =
          *(const f32x4*)(ep + lin);
    }
  }
}

// ---------------------------------------------------------------------------
// softmax over rows of fbuf (f32, len 2048); writes fp16 probabilities
// in-place over the start of each row (row stride stays 2048 f32).
// ---------------------------------------------------------------------------
__global__ __launch_bounds__(256) void k_softmax(float* fbuf)
{
  long row = blockIdx.x;
  float* rp = fbuf + row * N_;
  int t = threadIdx.x, lane = t & 63, wid = t >> 6;
  f32x4 a = *(const f32x4*)(rp + t * 8);
  f32x4 c = *(const f32x4*)(rp + t * 8 + 4);
  float m = fmaxf(fmaxf(fmaxf(a[0], a[1]), fmaxf(a[2], a[3])),
                  fmaxf(fmaxf(c[0], c[1]), fmaxf(c[2], c[3])));
#pragma unroll
  for (int o = 1; o < 64; o <<= 1) m = fmaxf(m, __shfl_xor(m, o));
  __shared__ float red[8];
  if (lane == 0) red[wid] = m;
  __syncthreads();
  m = fmaxf(fmaxf(red[0], red[1]), fmaxf(red[2], red[3]));
  float e[8];
  e[0] = __expf(a[0] - m); e[1] = __expf(a[1] - m);
  e[2] = __expf(a[2] - m); e[3] = __expf(a[3] - m);
  e[4] = __expf(c[0] - m); e[5] = __expf(c[1] - m);
  e[6] = __expf(c[2] - m); e[7] = __expf(c[3] - m);
  float s = ((e[0] + e[1]) + (e[2] + e[3])) + ((e[4] + e[5]) + (e[6] + e[7]));
#pragma unroll
  for (int o = 1; o < 64; o <<= 1) s += __shfl_xor(s, o);
  if (lane == 0) red[4 + wid] = s;
  __syncthreads();
  s = (red[4] + red[5]) + (red[6] + red[7]);
  float inv = 1.0f / s;
  f16x8 ph;
#pragma unroll
  for (int k = 0; k < 8; ++k) ph[k] = (half_t)(e[k] * inv);
  *(f16x8*)((half_t*)rp + t * 8) = ph;
}

// ---------------------------------------------------------------------------
// PV: y[b, c0+nloc, ci] (f16) = sum_m P[b,nloc,m] * gmat[b,ci,m]
// P rows live at stride 4096 f16 inside fbuf.
// ---------------------------------------------------------------------------
__global__ __launch_bounds__(256) void k_pv(
    const half_t* P, const half_t* gmat, half_t* ybuf, int c0, int rows)
{
  __shared__ __align__(16) char smem[32768];
  half_t* lA = (half_t*)smem;
  half_t* lB = (half_t*)(smem + 16384);
  float*  ep = (float*)smem;

  int b = blockIdx.z, m0 = blockIdx.y * 128, n0 = blockIdx.x * 128;
  f32x4 acc[4][4];
  zero_acc(acc);
  gemm128(P + ((long)b * rows + m0) * (N_ * 2), N_ * 2,
          gmat + ((long)b * CI_ + n0) * N_,     N_, N_, lA, lB, acc);

  int lane = threadIdx.x & 63, wid = threadIdx.x >> 6;
  int wm = wid >> 1, wn = wid & 1;
  int t = threadIdx.x;
#pragma unroll
  for (int pass = 0; pass < 2; ++pass) {
    __syncthreads();
    dump_acc(ep, acc, wm, wn, lane, pass, nullptr);
    __syncthreads();
#pragma unroll
    for (int k = 0; k < 8; ++k) {
      int lin = t * 4 + k * 1024;
      int row = lin >> 7, col = lin & 127;
      int nr = c0 + m0 + pass * 64 + row;
      f32x4 v = *(const f32x4*)(ep + lin);
      f16x4 w = { (half_t)v[0], (half_t)v[1], (half_t)v[2], (half_t)v[3] };
      *(f16x4*)(ybuf + ((long)b * N_ + nr) * CI_ + n0 + col) = w;
    }
  }
}

// ---------------------------------------------------------------------------
// final: out[b,o,n] = acc(Wfin[o,:].y[b,n,:]) * bnA[o] + bnB[o] + x[b,o,n]
// ---------------------------------------------------------------------------
__global__ __launch_bounds__(256) void k_final(
    const half_t* Wfin, const half_t* ybuf,
    const float* bnA, const float* bnB, const float* x, float* out)
{
  __shared__ __align__(16) char smem[32768];
  half_t* lA = (half_t*)smem;
  half_t* lB = (half_t*)(smem + 16384);
  float*  ep = (float*)smem;

  int b = blockIdx.z, m0 = blockIdx.y * 128, n0 = blockIdx.x * 128;
  f32x4 acc[4][4];
  zero_acc(acc);
  gemm128(Wfin + (long)m0 * CI_, CI_,
          ybuf + ((long)b * N_ + n0) * CI_, CI_, CI_, lA, lB, acc);

  int lane = threadIdx.x & 63, wid = threadIdx.x >> 6;
  int wm = wid >> 1, wn = wid & 1;
  int t = threadIdx.x;
#pragma unroll
  for (int pass = 0; pass < 2; ++pass) {
    __syncthreads();
    dump_acc(ep, acc, wm, wn, lane, pass, nullptr);
    __syncthreads();
#pragma unroll
    for (int k = 0; k < 8; ++k) {
      int lin = t * 4 + k * 1024;
      int row = lin >> 7, col = lin & 127;
      int o = m0 + pass * 64 + row;
      long idx = ((long)b * C_ + o) * N_ + n0 + col;
      f32x4 v  = *(const f32x4*)(ep + lin);
      f32x4 xi = *(const f32x4*)(x + idx);
      float sA = bnA[o], sB = bnB[o];
      f32x4 w = { v[0] * sA + sB + xi[0], v[1] * sA + sB + xi[1],
                  v[2] * sA + sB + xi[2], v[3] * sA + sB + xi[3] };
      *(f32x4*)(out + idx) = w;
    }
  }
}

// ---------------------------------------------------------------------------
extern "C" void kernel_launch(void* const* d_in, const int* in_sizes, int n_in,
                              void* d_out, int out_size, void* d_ws, size_t ws_size,
                              hipStream_t stream)
{
  const float* x       = (const float*)d_in[0];
  const float* g_w     = (const float*)d_in[1];
  const float* g_b     = (const float*)d_in[2];
  const float* theta_w = (const float*)d_in[3];
  const float* theta_b = (const float*)d_in[4];
  const float* phi_w   = (const float*)d_in[5];
  const float* phi_b   = (const float*)d_in[6];
  const float* W_w     = (const float*)d_in[7];
  const float* W_b     = (const float*)d_in[8];
  const float* gamma   = (const float*)d_in[9];
  const float* beta    = (const float*)d_in[10];
  const float* mean    = (const float*)d_in[11];
  const float* var     = (const float*)d_in[12];
  float* out = (float*)d_out;

  char* p = (char*)d_ws;
  auto alloc = [&](size_t bytes) {
    char* r = p; p += (bytes + 255) & ~(size_t)255; return r;
  };
  half_t* xT     = (half_t*)alloc((size_t)B_ * N_ * C_ * 2);
  half_t* Wcat   = (half_t*)alloc((size_t)1536 * C_ * 2);
  half_t* Wfin   = (half_t*)alloc((size_t)C_ * CI_ * 2);
  half_t* thetaT = (half_t*)alloc((size_t)B_ * N_ * CI_ * 2);
  half_t* phiT   = (half_t*)alloc((size_t)B_ * N_ * CI_ * 2);
  half_t* gmat   = (half_t*)alloc((size_t)B_ * CI_ * N_ * 2);
  half_t* ybuf   = (half_t*)alloc((size_t)B_ * N_ * CI_ * 2);
  float*  bnA    = (float*)alloc(C_ * 4);
  float*  bnB    = (float*)alloc(C_ * 4);
  size_t fixed = (size_t)(p - (char*)d_ws);

  int rows;
  if      (fixed + (size_t)B_ * 2048 * N_ * 4 <= ws_size) rows = 2048;
  else if (fixed + (size_t)B_ * 1024 * N_ * 4 <= ws_size) rows = 1024;
  else if (fixed + (size_t)B_ *  512 * N_ * 4 <= ws_size) rows = 512;
  else if (fixed + (size_t)B_ *  256 * N_ * 4 <= ws_size) rows = 256;
  else rows = 128;
  float* fbuf = (float*)alloc((size_t)B_ * rows * N_ * 4);

  k_prep<<<dim3((4 * CI_ * C_ + C_) / 256 + 1), 256, 0, stream>>>(
      theta_w, phi_w, g_w, W_w, W_b, gamma, beta, mean, var, Wcat, Wfin, bnA, bnB);
  k_transpose<<<dim3(N_ / 32, C_ / 32, B_), dim3(32, 8), 0, stream>>>(x, xT);
  k_proj<<<dim3(N_ / 128, 1536 / 128, B_), 256, 0, stream>>>(
      Wcat, xT, theta_b, phi_b, g_b, thetaT, phiT, gmat);
  for (int c0 = 0; c0 < N_; c0 += rows) {
    k_qk<<<dim3(N_ / 128, rows / 128, B_), 256, 0, stream>>>(thetaT, phiT, fbuf, c0, rows);
    k_softmax<<<dim3(B_ * rows), 256, 0, stream>>>(fbuf);
    k_pv<<<dim3(CI_ / 128, rows / 128, B_), 256, 0, stream>>>(
        (const half_t*)fbuf, gmat, ybuf, c0, rows);
  }
  k_final<<<dim3(N_ / 128, C_ / 128, B_), 256, 0, stream>>>(Wfin, ybuf, bnA, bnB, x, out);
}

// Round 8
// 416.928 us; speedup vs baseline: 1.1346x; 1.0430x over previous
//
#include <hip/hip_runtime.h>

// ---------------------------------------------------------------------------
// NonLocalBlockND: B=8, C=1024, Ci=512, N=T*H*W=2048
// fp16 MFMA GEMMs (128x128xBK64, global_load_lds 16B), fp32 scores+softmax,
// LDS-staged coalesced epilogues (R4).
// R6: T2 XOR-swizzle on mainloop LDS (rule #21: pre-swizzled GLOBAL source +
// swizzled LDS READ, linear LDS dest). Fixes 16-way ds_read_b128 bank
// conflict (SQ_LDS_BANK_CONFLICT was 2.0e7/dispatch on k_proj @ 21% mfma).
// ---------------------------------------------------------------------------

#define B_  8
#define C_  1024
#define CI_ 512
#define N_  2048

typedef _Float16 half_t;
typedef __attribute__((ext_vector_type(8))) _Float16 f16x8;
typedef __attribute__((ext_vector_type(4))) _Float16 f16x4;
typedef __attribute__((ext_vector_type(4))) float     f32x4;

__device__ __forceinline__ void gload16(const void* g, void* l) {
  __builtin_amdgcn_global_load_lds(
      (__attribute__((address_space(1))) unsigned int*)(g),
      (__attribute__((address_space(3))) unsigned int*)(l),
      16, 0, 0);
}

// ---------------------------------------------------------------------------
// 128x128 tile GEMM mainloop, BK=64, 256 threads (4 waves, 2x2 wave grid).
// A:(M,K) K-contig; B:(N,K) K-contig; C = A*B^T.
// LDS tile row-major [128][64 halves]; 16B slot s of row r holds GLOBAL slot
// s^(r&7)  (XOR involution; staged via pre-swizzled global address, read via
// swizzled LDS offset -> 2 lanes/bank, conflict-free).
// ---------------------------------------------------------------------------
__device__ __forceinline__ void gemm128(const half_t* Ag, long lda,
                                        const half_t* Bg, long ldb,
                                        int K,
                                        half_t* lA, half_t* lB,
                                        f32x4 acc[4][4])
{
  const int tid  = threadIdx.x;
  const int lane = tid & 63;
  const int wid  = tid >> 6;
  const int wm   = wid >> 1, wn = wid & 1;
  const int frow = lane & 15;          // row within 16x16 fragment
  const int g4   = lane >> 4;          // 16-lane group 0..3

  for (int k0 = 0; k0 < K; k0 += 64) {
#pragma unroll
    for (int it = 0; it < 4; ++it) {
      int c = it * 256 + tid;                       // chunk id (linear LDS)
      int row = c >> 3, slot = (c & 7) ^ (row & 7); // swizzled global slot
      gload16(Ag + (long)row * lda + (k0 + slot * 8), (char*)lA + c * 16);
    }
#pragma unroll
    for (int it = 0; it < 4; ++it) {
      int c = it * 256 + tid;
      int row = c >> 3, slot = (c & 7) ^ (row & 7);
      gload16(Bg + (long)row * ldb + (k0 + slot * 8), (char*)lB + c * 16);
    }
    __syncthreads();
#pragma unroll
    for (int kk = 0; kk < 2; ++kk) {
      f16x8 af[4], bfr[4];
#pragma unroll
      for (int i = 0; i < 4; ++i) {
        int row  = wm * 64 + i * 16 + frow;
        int slot = (kk * 4 + g4) ^ (row & 7);       // matching read swizzle
        af[i] = *(const f16x8*)(lA + row * 64 + slot * 8);
      }
#pragma unroll
      for (int j = 0; j < 4; ++j) {
        int row  = wn * 64 + j * 16 + frow;
        int slot = (kk * 4 + g4) ^ (row & 7);
        bfr[j] = *(const f16x8*)(lB + row * 64 + slot * 8);
      }
#pragma unroll
      for (int i = 0; i < 4; ++i)
#pragma unroll
        for (int j = 0; j < 4; ++j)
          acc[i][j] = __builtin_amdgcn_mfma_f32_16x16x32_f16(af[i], bfr[j], acc[i][j], 0, 0, 0);
    }
    __syncthreads();
  }
}

__device__ __forceinline__ void zero_acc(f32x4 acc[4][4]) {
  f32x4 z = {0.f, 0.f, 0.f, 0.f};
#pragma unroll
  for (int i = 0; i < 4; ++i)
#pragma unroll
    for (int j = 0; j < 4; ++j) acc[i][j] = z;
}

// Dump one wave's 64x64 acc tile into ep[64][128] (f32) if wm==pass.
__device__ __forceinline__ void dump_acc(float* ep, const f32x4 acc[4][4],
                                         int wm, int wn, int lane, int pass,
                                         const float* bias_row)
{
  if (wm != pass) return;
  int r4 = (lane >> 4) * 4, cc = lane & 15;
#pragma unroll
  for (int i = 0; i < 4; ++i) {
#pragma unroll
    for (int r = 0; r < 4; ++r) {
      int row = i * 16 + r4 + r;
      float bv = bias_row ? bias_row[row] : 0.0f;
#pragma unroll
      for (int j = 0; j < 4; ++j)
        ep[row * 128 + wn * 64 + j * 16 + cc] = acc[i][j][r] + bv;
    }
  }
}

// ---------------------------------------------------------------------------
// prep: cast weights to fp16; fold BN+bias into per-channel scale/shift.
// ---------------------------------------------------------------------------
__global__ __launch_bounds__(256) void k_prep(
    const float* theta_w, const float* phi_w, const float* g_w,
    const float* W_w, const float* W_b,
    const float* gamma, const float* beta, const float* mean, const float* var,
    half_t* Wcat, half_t* Wfin, float* bnA, float* bnB)
{
  const int PW = CI_ * C_;
  int idx = blockIdx.x * 256 + threadIdx.x;
  if (idx < PW)               Wcat[idx] = (half_t)theta_w[idx];
  else if (idx < 2 * PW)      Wcat[idx] = (half_t)phi_w[idx - PW];
  else if (idx < 3 * PW)      Wcat[idx] = (half_t)g_w[idx - 2 * PW];
  else if (idx < 4 * PW)      Wfin[idx - 3 * PW] = (half_t)W_w[idx - 3 * PW];
  else if (idx < 4 * PW + C_) {
    int o = idx - 4 * PW;
    float sc = gamma[o] * rsqrtf(var[o] + 1e-5f);
    bnA[o] = sc;
    bnB[o] = (W_b[o] - mean[o]) * sc + beta[o];
  }
}

// ---------------------------------------------------------------------------
// transpose+cast: x (B,C,N) f32 -> xT (B,N,C) f16
// ---------------------------------------------------------------------------
__global__ __launch_bounds__(256) void k_transpose(const float* x, half_t* xT)
{
  __shared__ float t[32][33];
  int b = blockIdx.z, c0 = blockIdx.y * 32, n0 = blockIdx.x * 32;
  int tx = threadIdx.x, ty = threadIdx.y;
  const float* xp = x + ((long)b * C_ + c0) * N_ + n0;
#pragma unroll
  for (int j = 0; j < 4; ++j)
    t[ty + j * 8][tx] = xp[(long)(ty + j * 8) * N_ + tx];
  __syncthreads();
  half_t* xo = xT + ((long)b * N_ + n0) * C_ + c0;
#pragma unroll
  for (int j = 0; j < 4; ++j)
    xo[(long)(ty + j * 8) * C_ + tx] = (half_t)t[tx][ty + j * 8];
}

// ---------------------------------------------------------------------------
// projections: Wcat(1536,1024) @ xT[b](2048,1024)^T, LDS-staged epilogues.
// ---------------------------------------------------------------------------
__global__ __launch_bounds__(256) void k_proj(
    const half_t* Wcat, const half_t* xT,
    const float* theta_b, const float* phi_b, const float* g_b,
    half_t* thetaT, half_t* phiT, half_t* gmat)
{
  __shared__ __align__(16) char smem[32768];
  half_t* lA = (half_t*)smem;
  half_t* lB = (half_t*)(smem + 16384);
  float*  ep = (float*)smem;

  int b = blockIdx.z, m0 = blockIdx.y * 128, n0 = blockIdx.x * 128;
  f32x4 acc[4][4];
  zero_acc(acc);
  gemm128(Wcat + (long)m0 * C_, C_, xT + ((long)b * N_ + n0) * C_, C_, C_, lA, lB, acc);

  int lane = threadIdx.x & 63, wid = threadIdx.x >> 6;
  int wm = wid >> 1, wn = wid & 1;
  int t = threadIdx.x;

  const float* bias = (m0 < 512) ? theta_b : (m0 < 1024) ? phi_b : g_b;
  int m0sub = (m0 < 512) ? m0 : (m0 < 1024) ? m0 - 512 : m0 - 1024;

#pragma unroll
  for (int pass = 0; pass < 2; ++pass) {
    __syncthreads();
    dump_acc(ep, acc, wm, wn, lane, pass, bias + m0sub + pass * 64);
    __syncthreads();
    if (m0 < 1024) {
      // transposed readout: out[n0+ncol][o] f16, contiguous along o.
      half_t* basep = (m0 < 512) ? thetaT : phiT;
      int ncol = t >> 1, ob = (t & 1) * 32;
      half_t* dst = basep + ((long)b * N_ + n0 + ncol) * CI_
                          + (m0sub + pass * 64 + ob);
#pragma unroll
      for (int k2 = 0; k2 < 4; ++k2) {
        f16x8 w;
#pragma unroll
        for (int e = 0; e < 8; ++e)
          w[e] = (half_t)ep[(ob + k2 * 8 + e) * 128 + ncol];
        *(f16x8*)(dst + k2 * 8) = w;
      }
    } else {
      // row-major readout: gmat[(b*CI+o)*N + n0+col] f16.
#pragma unroll
      for (int k = 0; k < 8; ++k) {
        int lin = t * 4 + k * 1024;
        int row = lin >> 7, col = lin & 127;
        int o = m0sub + pass * 64 + row;
        f32x4 v = *(const f32x4*)(ep + lin);
        f16x4 w = { (half_t)v[0], (half_t)v[1], (half_t)v[2], (half_t)v[3] };
        *(f16x4*)(gmat + ((long)b * CI_ + o) * N_ + n0 + col) = w;
      }
    }
  }
}

// ---------------------------------------------------------------------------
// scores: f[b, nloc, m] (f32) = thetaT[b, c0+nloc, :] . phiT[b, m, :]
// ---------------------------------------------------------------------------
__global__ __launch_bounds__(256) void k_qk(
    const half_t* thetaT, const half_t* phiT, float* fbuf, int c0, int rows)
{
  __shared__ __align__(16) char smem[32768];
  half_t* lA = (half_t*)smem;
  half_t* lB = (half_t*)(smem + 16384);
  float*  ep = (float*)smem;

  int b = blockIdx.z, m0 = blockIdx.y * 128, n0 = blockIdx.x * 128;
  f32x4 acc[4][4];
  zero_acc(acc);
  gemm128(thetaT + ((long)b * N_ + c0 + m0) * CI_, CI_,
          phiT   + ((long)b * N_ + n0) * CI_,      CI_, CI_, lA, lB, acc);

  int lane = threadIdx.x & 63, wid = threadIdx.x >> 6;
  int wm = wid >> 1, wn = wid & 1;
  int t = threadIdx.x;
#pragma unroll
  for (int pass = 0; pass < 2; ++pass) {
    __syncthreads();
    dump_acc(ep, acc, wm, wn, lane, pass, nullptr);
    __syncthreads();
#pragma unroll
    for (int k = 0; k < 8; ++k) {
      int lin = t * 4 + k * 1024;
      int row = lin >> 7, col = lin & 127;
      int mr = m0 + pass * 64 + row;
      *(f32x4*)(fbuf + ((long)b * rows + mr) * N_ + n0 + col) =
          *(const f32x4*)(ep + lin);
    }
  }
}

// ---------------------------------------------------------------------------
// softmax over rows of fbuf (f32, len 2048); writes fp16 probabilities
// in-place over the start of each row (row stride stays 2048 f32).
// ---------------------------------------------------------------------------
__global__ __launch_bounds__(256) void k_softmax(float* fbuf)
{
  long row = blockIdx.x;
  float* rp = fbuf + row * N_;
  int t = threadIdx.x, lane = t & 63, wid = t >> 6;
  f32x4 a = *(const f32x4*)(rp + t * 8);
  f32x4 c = *(const f32x4*)(rp + t * 8 + 4);
  float m = fmaxf(fmaxf(fmaxf(a[0], a[1]), fmaxf(a[2], a[3])),
                  fmaxf(fmaxf(c[0], c[1]), fmaxf(c[2], c[3])));
#pragma unroll
  for (int o = 1; o < 64; o <<= 1) m = fmaxf(m, __shfl_xor(m, o));
  __shared__ float red[8];
  if (lane == 0) red[wid] = m;
  __syncthreads();
  m = fmaxf(fmaxf(red[0], red[1]), fmaxf(red[2], red[3]));
  float e[8];
  e[0] = __expf(a[0] - m); e[1] = __expf(a[1] - m);
  e[2] = __expf(a[2] - m); e[3] = __expf(a[3] - m);
  e[4] = __expf(c[0] - m); e[5] = __expf(c[1] - m);
  e[6] = __expf(c[2] - m); e[7] = __expf(c[3] - m);
  float s = ((e[0] + e[1]) + (e[2] + e[3])) + ((e[4] + e[5]) + (e[6] + e[7]));
#pragma unroll
  for (int o = 1; o < 64; o <<= 1) s += __shfl_xor(s, o);
  if (lane == 0) red[4 + wid] = s;
  __syncthreads();
  s = (red[4] + red[5]) + (red[6] + red[7]);
  float inv = 1.0f / s;
  f16x8 ph;
#pragma unroll
  for (int k = 0; k < 8; ++k) ph[k] = (half_t)(e[k] * inv);
  *(f16x8*)((half_t*)rp + t * 8) = ph;
}

// ---------------------------------------------------------------------------
// PV: y[b, c0+nloc, ci] (f16) = sum_m P[b,nloc,m] * gmat[b,ci,m]
// P rows live at stride 4096 f16 inside fbuf.
// ---------------------------------------------------------------------------
__global__ __launch_bounds__(256) void k_pv(
    const half_t* P, const half_t* gmat, half_t* ybuf, int c0, int rows)
{
  __shared__ __align__(16) char smem[32768];
  half_t* lA = (half_t*)smem;
  half_t* lB = (half_t*)(smem + 16384);
  float*  ep = (float*)smem;

  int b = blockIdx.z, m0 = blockIdx.y * 128, n0 = blockIdx.x * 128;
  f32x4 acc[4][4];
  zero_acc(acc);
  gemm128(P + ((long)b * rows + m0) * (N_ * 2), N_ * 2,
          gmat + ((long)b * CI_ + n0) * N_,     N_, N_, lA, lB, acc);

  int lane = threadIdx.x & 63, wid = threadIdx.x >> 6;
  int wm = wid >> 1, wn = wid & 1;
  int t = threadIdx.x;
#pragma unroll
  for (int pass = 0; pass < 2; ++pass) {
    __syncthreads();
    dump_acc(ep, acc, wm, wn, lane, pass, nullptr);
    __syncthreads();
#pragma unroll
    for (int k = 0; k < 8; ++k) {
      int lin = t * 4 + k * 1024;
      int row = lin >> 7, col = lin & 127;
      int nr = c0 + m0 + pass * 64 + row;
      f32x4 v = *(const f32x4*)(ep + lin);
      f16x4 w = { (half_t)v[0], (half_t)v[1], (half_t)v[2], (half_t)v[3] };
      *(f16x4*)(ybuf + ((long)b * N_ + nr) * CI_ + n0 + col) = w;
    }
  }
}

// ---------------------------------------------------------------------------
// final: out[b,o,n] = acc(Wfin[o,:].y[b,n,:]) * bnA[o] + bnB[o] + x[b,o,n]
// ---------------------------------------------------------------------------
__global__ __launch_bounds__(256) void k_final(
    const half_t* Wfin, const half_t* ybuf,
    const float* bnA, const float* bnB, const float* x, float* out)
{
  __shared__ __align__(16) char smem[32768];
  half_t* lA = (half_t*)smem;
  half_t* lB = (half_t*)(smem + 16384);
  float*  ep = (float*)smem;

  int b = blockIdx.z, m0 = blockIdx.y * 128, n0 = blockIdx.x * 128;
  f32x4 acc[4][4];
  zero_acc(acc);
  gemm128(Wfin + (long)m0 * CI_, CI_,
          ybuf + ((long)b * N_ + n0) * CI_, CI_, CI_, lA, lB, acc);

  int lane = threadIdx.x & 63, wid = threadIdx.x >> 6;
  int wm = wid >> 1, wn = wid & 1;
  int t = threadIdx.x;
#pragma unroll
  for (int pass = 0; pass < 2; ++pass) {
    __syncthreads();
    dump_acc(ep, acc, wm, wn, lane, pass, nullptr);
    __syncthreads();
#pragma unroll
    for (int k = 0; k < 8; ++k) {
      int lin = t * 4 + k * 1024;
      int row = lin >> 7, col = lin & 127;
      int o = m0 + pass * 64 + row;
      long idx = ((long)b * C_ + o) * N_ + n0 + col;
      f32x4 v  = *(const f32x4*)(ep + lin);
      f32x4 xi = *(const f32x4*)(x + idx);
      float sA = bnA[o], sB = bnB[o];
      f32x4 w = { v[0] * sA + sB + xi[0], v[1] * sA + sB + xi[1],
                  v[2] * sA + sB + xi[2], v[3] * sA + sB + xi[3] };
      *(f32x4*)(out + idx) = w;
    }
  }
}

// ---------------------------------------------------------------------------
extern "C" void kernel_launch(void* const* d_in, const int* in_sizes, int n_in,
                              void* d_out, int out_size, void* d_ws, size_t ws_size,
                              hipStream_t stream)
{
  const float* x       = (const float*)d_in[0];
  const float* g_w     = (const float*)d_in[1];
  const float* g_b     = (const float*)d_in[2];
  const float* theta_w = (const float*)d_in[3];
  const float* theta_b = (const float*)d_in[4];
  const float* phi_w   = (const float*)d_in[5];
  const float* phi_b   = (const float*)d_in[6];
  const float* W_w     = (const float*)d_in[7];
  const float* W_b     = (const float*)d_in[8];
  const float* gamma   = (const float*)d_in[9];
  const float* beta    = (const float*)d_in[10];
  const float* mean    = (const float*)d_in[11];
  const float* var     = (const float*)d_in[12];
  float* out = (float*)d_out;

  char* p = (char*)d_ws;
  auto alloc = [&](size_t bytes) {
    char* r = p; p += (bytes + 255) & ~(size_t)255; return r;
  };
  half_t* xT     = (half_t*)alloc((size_t)B_ * N_ * C_ * 2);
  half_t* Wcat   = (half_t*)alloc((size_t)1536 * C_ * 2);
  half_t* Wfin   = (half_t*)alloc((size_t)C_ * CI_ * 2);
  half_t* thetaT = (half_t*)alloc((size_t)B_ * N_ * CI_ * 2);
  half_t* phiT   = (half_t*)alloc((size_t)B_ * N_ * CI_ * 2);
  half_t* gmat   = (half_t*)alloc((size_t)B_ * CI_ * N_ * 2);
  half_t* ybuf   = (half_t*)alloc((size_t)B_ * N_ * CI_ * 2);
  float*  bnA    = (float*)alloc(C_ * 4);
  float*  bnB    = (float*)alloc(C_ * 4);
  size_t fixed = (size_t)(p - (char*)d_ws);

  int rows;
  if      (fixed + (size_t)B_ * 2048 * N_ * 4 <= ws_size) rows = 2048;
  else if (fixed + (size_t)B_ * 1024 * N_ * 4 <= ws_size) rows = 1024;
  else if (fixed + (size_t)B_ *  512 * N_ * 4 <= ws_size) rows = 512;
  else if (fixed + (size_t)B_ *  256 * N_ * 4 <= ws_size) rows = 256;
  else rows = 128;
  float* fbuf = (float*)alloc((size_t)B_ * rows * N_ * 4);

  k_prep<<<dim3((4 * CI_ * C_ + C_) / 256 + 1), 256, 0, stream>>>(
      theta_w, phi_w, g_w, W_w, W_b, gamma, beta, mean, var, Wcat, Wfin, bnA, bnB);
  k_transpose<<<dim3(N_ / 32, C_ / 32, B_), dim3(32, 8), 0, stream>>>(x, xT);
  k_proj<<<dim3(N_ / 128, 1536 / 128, B_), 256, 0, stream>>>(
      Wcat, xT, theta_b, phi_b, g_b, thetaT, phiT, gmat);
  for (int c0 = 0; c0 < N_; c0 += rows) {
    k_qk<<<dim3(N_ / 128, rows / 128, B_), 256, 0, stream>>>(thetaT, phiT, fbuf, c0, rows);
    k_softmax<<<dim3(B_ * rows), 256, 0, stream>>>(fbuf);
    k_pv<<<dim3(CI_ / 128, rows / 128, B_), 256, 0, stream>>>(
        (const half_t*)fbuf, gmat, ybuf, c0, rows);
  }
  k_final<<<dim3(N_ / 128, C_ / 128, B_), 256, 0, stream>>>(Wfin, ybuf, bnA, bnB, x, out);
}

// Round 10
// 388.731 us; speedup vs baseline: 1.2169x; 1.0725x over previous
//
#include <hip/hip_runtime.h>

// ---------------------------------------------------------------------------
// NonLocalBlockND: B=8, C=1024, Ci=512, N=T*H*W=2048
// fp16 MFMA GEMMs, fp32 scores+softmax, LDS-staged coalesced epilogues (R4),
// T2 XOR-swizzle on mainloop LDS (R6: conflicts 2.0e7 -> 1.3e6).
// R9: DOUBLE-BUFFERED mainloop (T3 minimum-2-phase): issue next tile's
// global_load_lds BEFORE computing current tile -> HBM latency hides under
// MFMA phase. (R8 PMC: conflicts collapsed but k_proj only 97->83us, 2-barrier
// serial stage was critical path per m233.)
// ---------------------------------------------------------------------------

#define B_  8
#define C_  1024
#define CI_ 512
#define N_  2048

typedef _Float16 half_t;
typedef __attribute__((ext_vector_type(8))) _Float16 f16x8;
typedef __attribute__((ext_vector_type(4))) _Float16 f16x4;
typedef __attribute__((ext_vector_type(4))) float     f32x4;

__device__ __forceinline__ void gload16(const void* g, void* l) {
  __builtin_amdgcn_global_load_lds(
      (__attribute__((address_space(1))) unsigned int*)(g),
      (__attribute__((address_space(3))) unsigned int*)(l),
      16, 0, 0);
}

// ---------------------------------------------------------------------------
// 128x128 tile GEMM mainloop, BK=64, 256 threads (4 waves, 2x2 wave grid).
// A:(M,K) K-contig; B:(N,K) K-contig; C = A*B^T.
// Double-buffered LDS: buf p at lds + p*16384 halves (lA 8192, lB 8192).
// Swizzle: LDS slot s of row r holds global slot s^(r&7) (XOR involution,
// staged via pre-swizzled global address; linear LDS dest for gload_lds).
// Loop: {stage(t+1 into buf^1); compute(t from buf); barrier} — stage issue
// precedes compute so the load latency overlaps the MFMA phase; the single
// barrier (vmcnt0+lgkm0) makes buf^1 ready and buf safe to restage.
// ---------------------------------------------------------------------------
__device__ __forceinline__ void gemm128(const half_t* Ag, long lda,
                                        const half_t* Bg, long ldb,
                                        int K,
                                        half_t* lds,
                                        f32x4 acc[4][4])
{
  const int tid  = threadIdx.x;
  const int lane = tid & 63;
  const int wid  = tid >> 6;
  const int wm   = wid >> 1, wn = wid & 1;
  const int frow = lane & 15;          // row within 16x16 fragment
  const int g4   = lane >> 4;          // 16-lane group 0..3

  auto stage = [&](int p, int k0) {
    half_t* lA = lds + p * 16384;
    half_t* lB = lA + 8192;
#pragma unroll
    for (int it = 0; it < 4; ++it) {
      int c = it * 256 + tid;                        // chunk id (linear LDS)
      int row = c >> 3, slot = (c & 7) ^ (row & 7);  // swizzled global slot
      gload16(Ag + (long)row * lda + (k0 + slot * 8), (char*)lA + c * 16);
    }
#pragma unroll
    for (int it = 0; it < 4; ++it) {
      int c = it * 256 + tid;
      int row = c >> 3, slot = (c & 7) ^ (row & 7);
      gload16(Bg + (long)row * ldb + (k0 + slot * 8), (char*)lB + c * 16);
    }
  };

  stage(0, 0);
  __syncthreads();
  int cur = 0;
  for (int k0 = 64; k0 <= K; k0 += 64) {
    if (k0 < K) stage(cur ^ 1, k0);    // issue next tile BEFORE compute
    half_t* lA = lds + cur * 16384;
    half_t* lB = lA + 8192;
#pragma unroll
    for (int kk = 0; kk < 2; ++kk) {
      f16x8 af[4], bfr[4];
#pragma unroll
      for (int i = 0; i < 4; ++i) {
        int row  = wm * 64 + i * 16 + frow;
        int slot = (kk * 4 + g4) ^ (row & 7);        // matching read swizzle
        af[i] = *(const f16x8*)(lA + row * 64 + slot * 8);
      }
#pragma unroll
      for (int j = 0; j < 4; ++j) {
        int row  = wn * 64 + j * 16 + frow;
        int slot = (kk * 4 + g4) ^ (row & 7);
        bfr[j] = *(const f16x8*)(lB + row * 64 + slot * 8);
      }
#pragma unroll
      for (int i = 0; i < 4; ++i)
#pragma unroll
        for (int j = 0; j < 4; ++j)
          acc[i][j] = __builtin_amdgcn_mfma_f32_16x16x32_f16(af[i], bfr[j], acc[i][j], 0, 0, 0);
    }
    __syncthreads();                   // buf^1 ready; buf safe to restage
    cur ^= 1;
  }
}

__device__ __forceinline__ void zero_acc(f32x4 acc[4][4]) {
  f32x4 z = {0.f, 0.f, 0.f, 0.f};
#pragma unroll
  for (int i = 0; i < 4; ++i)
#pragma unroll
    for (int j = 0; j < 4; ++j) acc[i][j] = z;
}

// Dump one wave's 64x64 acc tile into ep[64][128] (f32) if wm==pass.
__device__ __forceinline__ void dump_acc(float* ep, const f32x4 acc[4][4],
                                         int wm, int wn, int lane, int pass,
                                         const float* bias_row)
{
  if (wm != pass) return;
  int r4 = (lane >> 4) * 4, cc = lane & 15;
#pragma unroll
  for (int i = 0; i < 4; ++i) {
#pragma unroll
    for (int r = 0; r < 4; ++r) {
      int row = i * 16 + r4 + r;
      float bv = bias_row ? bias_row[row] : 0.0f;
#pragma unroll
      for (int j = 0; j < 4; ++j)
        ep[row * 128 + wn * 64 + j * 16 + cc] = acc[i][j][r] + bv;
    }
  }
}

// ---------------------------------------------------------------------------
// prep: cast weights to fp16; fold BN+bias into per-channel scale/shift.
// ---------------------------------------------------------------------------
__global__ __launch_bounds__(256) void k_prep(
    const float* theta_w, const float* phi_w, const float* g_w,
    const float* W_w, const float* W_b,
    const float* gamma, const float* beta, const float* mean, const float* var,
    half_t* Wcat, half_t* Wfin, float* bnA, float* bnB)
{
  const int PW = CI_ * C_;
  int idx = blockIdx.x * 256 + threadIdx.x;
  if (idx < PW)               Wcat[idx] = (half_t)theta_w[idx];
  else if (idx < 2 * PW)      Wcat[idx] = (half_t)phi_w[idx - PW];
  else if (idx < 3 * PW)      Wcat[idx] = (half_t)g_w[idx - 2 * PW];
  else if (idx < 4 * PW)      Wfin[idx - 3 * PW] = (half_t)W_w[idx - 3 * PW];
  else if (idx < 4 * PW + C_) {
    int o = idx - 4 * PW;
    float sc = gamma[o] * rsqrtf(var[o] + 1e-5f);
    bnA[o] = sc;
    bnB[o] = (W_b[o] - mean[o]) * sc + beta[o];
  }
}

// ---------------------------------------------------------------------------
// transpose+cast: x (B,C,N) f32 -> xT (B,N,C) f16
// ---------------------------------------------------------------------------
__global__ __launch_bounds__(256) void k_transpose(const float* x, half_t* xT)
{
  __shared__ float t[32][33];
  int b = blockIdx.z, c0 = blockIdx.y * 32, n0 = blockIdx.x * 32;
  int tx = threadIdx.x, ty = threadIdx.y;
  const float* xp = x + ((long)b * C_ + c0) * N_ + n0;
#pragma unroll
  for (int j = 0; j < 4; ++j)
    t[ty + j * 8][tx] = xp[(long)(ty + j * 8) * N_ + tx];
  __syncthreads();
  half_t* xo = xT + ((long)b * N_ + n0) * C_ + c0;
#pragma unroll
  for (int j = 0; j < 4; ++j)
    xo[(long)(ty + j * 8) * C_ + tx] = (half_t)t[tx][ty + j * 8];
}

// ---------------------------------------------------------------------------
// projections: Wcat(1536,1024) @ xT[b](2048,1024)^T, LDS-staged epilogues.
// ---------------------------------------------------------------------------
__global__ __launch_bounds__(256) void k_proj(
    const half_t* Wcat, const half_t* xT,
    const float* theta_b, const float* phi_b, const float* g_b,
    half_t* thetaT, half_t* phiT, half_t* gmat)
{
  __shared__ __align__(16) char smem[65536];
  half_t* lds = (half_t*)smem;
  float*  ep  = (float*)smem;

  int b = blockIdx.z, m0 = blockIdx.y * 128, n0 = blockIdx.x * 128;
  f32x4 acc[4][4];
  zero_acc(acc);
  gemm128(Wcat + (long)m0 * C_, C_, xT + ((long)b * N_ + n0) * C_, C_, C_, lds, acc);

  int lane = threadIdx.x & 63, wid = threadIdx.x >> 6;
  int wm = wid >> 1, wn = wid & 1;
  int t = threadIdx.x;

  const float* bias = (m0 < 512) ? theta_b : (m0 < 1024) ? phi_b : g_b;
  int m0sub = (m0 < 512) ? m0 : (m0 < 1024) ? m0 - 512 : m0 - 1024;

#pragma unroll
  for (int pass = 0; pass < 2; ++pass) {
    __syncthreads();
    dump_acc(ep, acc, wm, wn, lane, pass, bias + m0sub + pass * 64);
    __syncthreads();
    if (m0 < 1024) {
      // transposed readout: out[n0+ncol][o] f16, contiguous along o.
      half_t* basep = (m0 < 512) ? thetaT : phiT;
      int ncol = t >> 1, ob = (t & 1) * 32;
      half_t* dst = basep + ((long)b * N_ + n0 + ncol) * CI_
                          + (m0sub + pass * 64 + ob);
#pragma unroll
      for (int k2 = 0; k2 < 4; ++k2) {
        f16x8 w;
#pragma unroll
        for (int e = 0; e < 8; ++e)
          w[e] = (half_t)ep[(ob + k2 * 8 + e) * 128 + ncol];
        *(f16x8*)(dst + k2 * 8) = w;
      }
    } else {
      // row-major readout: gmat[(b*CI+o)*N + n0+col] f16.
#pragma unroll
      for (int k = 0; k < 8; ++k) {
        int lin = t * 4 + k * 1024;
        int row = lin >> 7, col = lin & 127;
        int o = m0sub + pass * 64 + row;
        f32x4 v = *(const f32x4*)(ep + lin);
        f16x4 w = { (half_t)v[0], (half_t)v[1], (half_t)v[2], (half_t)v[3] };
        *(f16x4*)(gmat + ((long)b * CI_ + o) * N_ + n0 + col) = w;
      }
    }
  }
}

// ---------------------------------------------------------------------------
// scores: f[b, nloc, m] (f32) = thetaT[b, c0+nloc, :] . phiT[b, m, :]
// ---------------------------------------------------------------------------
__global__ __launch_bounds__(256) void k_qk(
    const half_t* thetaT, const half_t* phiT, float* fbuf, int c0, int rows)
{
  __shared__ __align__(16) char smem[65536];
  half_t* lds = (half_t*)smem;
  float*  ep  = (float*)smem;

  int b = blockIdx.z, m0 = blockIdx.y * 128, n0 = blockIdx.x * 128;
  f32x4 acc[4][4];
  zero_acc(acc);
  gemm128(thetaT + ((long)b * N_ + c0 + m0) * CI_, CI_,
          phiT   + ((long)b * N_ + n0) * CI_,      CI_, CI_, lds, acc);

  int lane = threadIdx.x & 63, wid = threadIdx.x >> 6;
  int wm = wid >> 1, wn = wid & 1;
  int t = threadIdx.x;
#pragma unroll
  for (int pass = 0; pass < 2; ++pass) {
    __syncthreads();
    dump_acc(ep, acc, wm, wn, lane, pass, nullptr);
    __syncthreads();
#pragma unroll
    for (int k = 0; k < 8; ++k) {
      int lin = t * 4 + k * 1024;
      int row = lin >> 7, col = lin & 127;
      int mr = m0 + pass * 64 + row;
      *(f32x4*)(fbuf + ((long)b * rows + mr) * N_ + n0 + col) =
          *(const f32x4*)(ep + lin);
    }
  }
}

// ---------------------------------------------------------------------------
// softmax over rows of fbuf (f32, len 2048); writes fp16 probabilities
// in-place over the start of each row (row stride stays 2048 f32).
// ---------------------------------------------------------------------------
__global__ __launch_bounds__(256) void k_softmax(float* fbuf)
{
  long row = blockIdx.x;
  float* rp = fbuf + row * N_;
  int t = threadIdx.x, lane = t & 63, wid = t >> 6;
  f32x4 a = *(const f32x4*)(rp + t * 8);
  f32x4 c = *(const f32x4*)(rp + t * 8 + 4);
  float m = fmaxf(fmaxf(fmaxf(a[0], a[1]), fmaxf(a[2], a[3])),
                  fmaxf(fmaxf(c[0], c[1]), fmaxf(c[2], c[3])));
#pragma unroll
  for (int o = 1; o < 64; o <<= 1) m = fmaxf(m, __shfl_xor(m, o));
  __shared__ float red[8];
  if (lane == 0) red[wid] = m;
  __syncthreads();
  m = fmaxf(fmaxf(red[0], red[1]), fmaxf(red[2], red[3]));
  float e[8];
  e[0] = __expf(a[0] - m); e[1] = __expf(a[1] - m);
  e[2] = __expf(a[2] - m); e[3] = __expf(a[3] - m);
  e[4] = __expf(c[0] - m); e[5] = __expf(c[1] - m);
  e[6] = __expf(c[2] - m); e[7] = __expf(c[3] - m);
  float s = ((e[0] + e[1]) + (e[2] + e[3])) + ((e[4] + e[5]) + (e[6] + e[7]));
#pragma unroll
  for (int o = 1; o < 64; o <<= 1) s += __shfl_xor(s, o);
  if (lane == 0) red[4 + wid] = s;
  __syncthreads();
  s = (red[4] + red[5]) + (red[6] + red[7]);
  float inv = 1.0f / s;
  f16x8 ph;
#pragma unroll
  for (int k = 0; k < 8; ++k) ph[k] = (half_t)(e[k] * inv);
  *(f16x8*)((half_t*)rp + t * 8) = ph;
}

// ---------------------------------------------------------------------------
// PV: y[b, c0+nloc, ci] (f16) = sum_m P[b,nloc,m] * gmat[b,ci,m]
// P rows live at stride 4096 f16 inside fbuf.
// ---------------------------------------------------------------------------
__global__ __launch_bounds__(256) void k_pv(
    const half_t* P, const half_t* gmat, half_t* ybuf, int c0, int rows)
{
  __shared__ __align__(16) char smem[65536];
  half_t* lds = (half_t*)smem;
  float*  ep  = (float*)smem;

  int b = blockIdx.z, m0 = blockIdx.y * 128, n0 = blockIdx.x * 128;
  f32x4 acc[4][4];
  zero_acc(acc);
  gemm128(P + ((long)b * rows + m0) * (N_ * 2), N_ * 2,
          gmat + ((long)b * CI_ + n0) * N_,     N_, N_, lds, acc);

  int lane = threadIdx.x & 63, wid = threadIdx.x >> 6;
  int wm = wid >> 1, wn = wid & 1;
  int t = threadIdx.x;
#pragma unroll
  for (int pass = 0; pass < 2; ++pass) {
    __syncthreads();
    dump_acc(ep, acc, wm, wn, lane, pass, nullptr);
    __syncthreads();
#pragma unroll
    for (int k = 0; k < 8; ++k) {
      int lin = t * 4 + k * 1024;
      int row = lin >> 7, col = lin & 127;
      int nr = c0 + m0 + pass * 64 + row;
      f32x4 v = *(const f32x4*)(ep + lin);
      f16x4 w = { (half_t)v[0], (half_t)v[1], (half_t)v[2], (half_t)v[3] };
      *(f16x4*)(ybuf + ((long)b * N_ + nr) * CI_ + n0 + col) = w;
    }
  }
}

// ---------------------------------------------------------------------------
// final: out[b,o,n] = acc(Wfin[o,:].y[b,n,:]) * bnA[o] + bnB[o] + x[b,o,n]
// ---------------------------------------------------------------------------
__global__ __launch_bounds__(256) void k_final(
    const half_t* Wfin, const half_t* ybuf,
    const float* bnA, const float* bnB, const float* x, float* out)
{
  __shared__ __align__(16) char smem[65536];
  half_t* lds = (half_t*)smem;
  float*  ep  = (float*)smem;

  int b = blockIdx.z, m0 = blockIdx.y * 128, n0 = blockIdx.x * 128;
  f32x4 acc[4][4];
  zero_acc(acc);
  gemm128(Wfin + (long)m0 * CI_, CI_,
          ybuf + ((long)b * N_ + n0) * CI_, CI_, CI_, lds, acc);

  int lane = threadIdx.x & 63, wid = threadIdx.x >> 6;
  int wm = wid >> 1, wn = wid & 1;
  int t = threadIdx.x;
#pragma unroll
  for (int pass = 0; pass < 2; ++pass) {
    __syncthreads();
    dump_acc(ep, acc, wm, wn, lane, pass, nullptr);
    __syncthreads();
#pragma unroll
    for (int k = 0; k < 8; ++k) {
      int lin = t * 4 + k * 1024;
      int row = lin >> 7, col = lin & 127;
      int o = m0 + pass * 64 + row;
      long idx = ((long)b * C_ + o) * N_ + n0 + col;
      f32x4 v  = *(const f32x4*)(ep + lin);
      f32x4 xi = *(const f32x4*)(x + idx);
      float sA = bnA[o], sB = bnB[o];
      f32x4 w = { v[0] * sA + sB + xi[0], v[1] * sA + sB + xi[1],
                  v[2] * sA + sB + xi[2], v[3] * sA + sB + xi[3] };
      *(f32x4*)(out + idx) = w;
    }
  }
}

// ---------------------------------------------------------------------------
extern "C" void kernel_launch(void* const* d_in, const int* in_sizes, int n_in,
                              void* d_out, int out_size, void* d_ws, size_t ws_size,
                              hipStream_t stream)
{
  const float* x       = (const float*)d_in[0];
  const float* g_w     = (const float*)d_in[1];
  const float* g_b     = (const float*)d_in[2];
  const float* theta_w = (const float*)d_in[3];
  const float* theta_b = (const float*)d_in[4];
  const float* phi_w   = (const float*)d_in[5];
  const float* phi_b   = (const float*)d_in[6];
  const float* W_w     = (const float*)d_in[7];
  const float* W_b     = (const float*)d_in[8];
  const float* gamma   = (const float*)d_in[9];
  const float* beta    = (const float*)d_in[10];
  const float* mean    = (const float*)d_in[11];
  const float* var     = (const float*)d_in[12];
  float* out = (float*)d_out;

  char* p = (char*)d_ws;
  auto alloc = [&](size_t bytes) {
    char* r = p; p += (bytes + 255) & ~(size_t)255; return r;
  };
  half_t* xT     = (half_t*)alloc((size_t)B_ * N_ * C_ * 2);
  half_t* Wcat   = (half_t*)alloc((size_t)1536 * C_ * 2);
  half_t* Wfin   = (half_t*)alloc((size_t)C_ * CI_ * 2);
  half_t* thetaT = (half_t*)alloc((size_t)B_ * N_ * CI_ * 2);
  half_t* phiT   = (half_t*)alloc((size_t)B_ * N_ * CI_ * 2);
  half_t* gmat   = (half_t*)alloc((size_t)B_ * CI_ * N_ * 2);
  half_t* ybuf   = (half_t*)alloc((size_t)B_ * N_ * CI_ * 2);
  float*  bnA    = (float*)alloc(C_ * 4);
  float*  bnB    = (float*)alloc(C_ * 4);
  size_t fixed = (size_t)(p - (char*)d_ws);

  int rows;
  if      (fixed + (size_t)B_ * 2048 * N_ * 4 <= ws_size) rows = 2048;
  else if (fixed + (size_t)B_ * 1024 * N_ * 4 <= ws_size) rows = 1024;
  else if (fixed + (size_t)B_ *  512 * N_ * 4 <= ws_size) rows = 512;
  else if (fixed + (size_t)B_ *  256 * N_ * 4 <= ws_size) rows = 256;
  else rows = 128;
  float* fbuf = (float*)alloc((size_t)B_ * rows * N_ * 4);

  k_prep<<<dim3((4 * CI_ * C_ + C_) / 256 + 1), 256, 0, stream>>>(
      theta_w, phi_w, g_w, W_w, W_b, gamma, beta, mean, var, Wcat, Wfin, bnA, bnB);
  k_transpose<<<dim3(N_ / 32, C_ / 32, B_), dim3(32, 8), 0, stream>>>(x, xT);
  k_proj<<<dim3(N_ / 128, 1536 / 128, B_), 256, 0, stream>>>(
      Wcat, xT, theta_b, phi_b, g_b, thetaT, phiT, gmat);
  for (int c0 = 0; c0 < N_; c0 += rows) {
    k_qk<<<dim3(N_ / 128, rows / 128, B_), 256, 0, stream>>>(thetaT, phiT, fbuf, c0, rows);
    k_softmax<<<dim3(B_ * rows), 256, 0, stream>>>(fbuf);
    k_pv<<<dim3(CI_ / 128, rows / 128, B_), 256, 0, stream>>>(
        (const half_t*)fbuf, gmat, ybuf, c0, rows);
  }
  k_final<<<dim3(N_ / 128, C_ / 128, B_), 256, 0, stream>>>(Wfin, ybuf, bnA, bnB, x, out);
}